// Round 1
// baseline (530.866 us; speedup 1.0000x reference)
//
#include <hip/hip_runtime.h>

typedef _Float16 h8 __attribute__((ext_vector_type(8)));
typedef _Float16 h4 __attribute__((ext_vector_type(4)));
typedef float fx4 __attribute__((ext_vector_type(4)));

#define D_ 1024
#define S_ 2048
#define H_ 8
#define HD_ 128
static constexpr float SCALE = 0.0883883476483184405f;  // 1/sqrt(128)

// ---------------- cast fp32 -> fp16 (vectorized) ----------------
__global__ void cast_f16_kernel(const float* __restrict__ x, _Float16* __restrict__ y, int n4) {
  int i = blockIdx.x * blockDim.x + threadIdx.x;
  if (i >= n4) return;
  float4 v = ((const float4*)x)[i];
  h4 o = { (_Float16)v.x, (_Float16)v.y, (_Float16)v.z, (_Float16)v.w };
  ((h4*)y)[i] = o;
}

// ---------------- transpose+cast weight: Wt[n][k] = W[k][n] ----------------
__global__ void transpose_cast_w(const float* __restrict__ W, _Float16* __restrict__ Wt) {
  __shared__ float tile[32][33];
  int bx = blockIdx.x * 32, by = blockIdx.y * 32;
  int tx = threadIdx.x, ty = threadIdx.y;
  for (int i = ty; i < 32; i += 8)
    tile[i][tx] = W[(by + i) * D_ + bx + tx];
  __syncthreads();
  for (int i = ty; i < 32; i += 8)
    Wt[(bx + i) * D_ + by + tx] = (_Float16)tile[tx][i];
}

// ---------------- transpose V: (B,S,H,HD) -> (B,H,HD,S) ----------------
__global__ void transpose_v(const _Float16* __restrict__ Vh, _Float16* __restrict__ Vt) {
  __shared__ _Float16 tile[32][33];
  int s0 = blockIdx.x * 32, d0 = blockIdx.y * 32;
  int bh = blockIdx.z;
  int b = bh >> 3, h = bh & 7;
  int tx = threadIdx.x, ty = threadIdx.y;
  for (int i = ty; i < 32; i += 8)
    tile[i][tx] = Vh[(b * S_ + s0 + i) * D_ + h * HD_ + d0 + tx];
  __syncthreads();
  for (int i = ty; i < 32; i += 8)
    Vt[(bh * HD_ + d0 + i) * S_ + s0 + tx] = tile[tx][i];
}

// ---------------- GEMM: C[M,N] = A[M,K] @ Bt[N,K]^T + bias ----------------
// 128x128 tile, BK=32, 256 threads = 4 waves (2x2), each wave 64x64 (4x4 of 16x16 MFMA).
template <typename OutT>
__device__ __forceinline__ void gemm_body(const _Float16* __restrict__ A,
                                          const _Float16* __restrict__ Bt,
                                          const float* __restrict__ bias,
                                          OutT* __restrict__ C, int m0, int n0) {
  constexpr int K = 1024, N = 1024;
  __shared__ __align__(16) _Float16 As[128 * 32];
  __shared__ __align__(16) _Float16 Bs[128 * 32];
  int tid = threadIdx.x;
  int lane = tid & 63, w = tid >> 6;
  int wr = w >> 1, wc = w & 1;
  int l16 = lane & 15, quad = lane >> 4;
  fx4 acc[4][4] = {};
  int f0 = tid * 8, f1 = (256 + tid) * 8;
  int rA0 = f0 >> 5, kk0 = f0 & 31;
  int rA1 = f1 >> 5, kk1 = f1 & 31;
  for (int k0 = 0; k0 < K; k0 += 32) {
    *(h8*)&As[f0] = *(const h8*)&A[(m0 + rA0) * K + k0 + kk0];
    *(h8*)&As[f1] = *(const h8*)&A[(m0 + rA1) * K + k0 + kk1];
    *(h8*)&Bs[f0] = *(const h8*)&Bt[(n0 + rA0) * K + k0 + kk0];
    *(h8*)&Bs[f1] = *(const h8*)&Bt[(n0 + rA1) * K + k0 + kk1];
    __syncthreads();
    h8 a[4], b[4];
#pragma unroll
    for (int i = 0; i < 4; ++i) a[i] = *(const h8*)&As[(wr * 64 + i * 16 + l16) * 32 + quad * 8];
#pragma unroll
    for (int j = 0; j < 4; ++j) b[j] = *(const h8*)&Bs[(wc * 64 + j * 16 + l16) * 32 + quad * 8];
#pragma unroll
    for (int i = 0; i < 4; ++i)
#pragma unroll
      for (int j = 0; j < 4; ++j)
        acc[i][j] = __builtin_amdgcn_mfma_f32_16x16x32_f16(a[i], b[j], acc[i][j], 0, 0, 0);
    __syncthreads();
  }
  // C/D layout (m89-verified): col = lane&15, row = (lane>>4)*4 + reg
#pragma unroll
  for (int i = 0; i < 4; ++i) {
    int row = m0 + wr * 64 + i * 16 + quad * 4;
#pragma unroll
    for (int j = 0; j < 4; ++j) {
      int col = n0 + wc * 64 + j * 16 + l16;
      float bv_ = bias[col];
#pragma unroll
      for (int r = 0; r < 4; ++r)
        C[(row + r) * N + col] = (OutT)(acc[i][j][r] + bv_);
    }
  }
}

__global__ __launch_bounds__(256) void gemm_qkv(const _Float16* __restrict__ A,
                                                const _Float16* __restrict__ Wt,
                                                const float* __restrict__ bq,
                                                const float* __restrict__ bk,
                                                const float* __restrict__ bv,
                                                _Float16* __restrict__ QKV) {
  int z = blockIdx.z;
  const float* bias = (z == 0) ? bq : ((z == 1) ? bk : bv);
  gemm_body<_Float16>(A, Wt + z * (D_ * D_), bias, QKV + z * (S_ * 4 * D_),
                      blockIdx.y * 128, blockIdx.x * 128);
}

__global__ __launch_bounds__(256) void gemm_out(const _Float16* __restrict__ A,
                                                const _Float16* __restrict__ Wt,
                                                const float* __restrict__ bias,
                                                float* __restrict__ C) {
  gemm_body<float>(A, Wt, bias, C, blockIdx.y * 128, blockIdx.x * 128);
}

// ---------------- flash attention ----------------
// Block: 4 waves, 64 q-rows (16 per wave). K-tiles of 64 keys. Grid: (S/64, B*H).
__global__ __launch_bounds__(256) void attn_kernel(const _Float16* __restrict__ Qh,
                                                   const _Float16* __restrict__ Kh,
                                                   const _Float16* __restrict__ Vt,  // (B,H,HD,S)
                                                   _Float16* __restrict__ Oh) {
  __shared__ __align__(16) _Float16 Ks[64 * 136];     // [key][d], padded
  __shared__ __align__(16) _Float16 Vs[128 * 72];     // [d][key], padded
  __shared__ __align__(16) _Float16 Ps[4 * 16 * 72];  // per-wave [q][key], padded
  int tid = threadIdx.x;
  int lane = tid & 63, w = tid >> 6;
  int l16 = lane & 15, quad = lane >> 4;
  int bh = blockIdx.y, b = bh >> 3, h = bh & 7;
  int q0 = blockIdx.x * 64 + w * 16;

  // Q fragments (A-operand layout: m = lane&15, k = quad*8 + j), held in regs
  h8 aq[4];
#pragma unroll
  for (int kk = 0; kk < 4; ++kk)
    aq[kk] = *(const h8*)&Qh[(b * S_ + q0 + l16) * D_ + h * HD_ + kk * 32 + quad * 8];

  float m_i[4], l_i[4];
  fx4 o[8] = {};
#pragma unroll
  for (int r = 0; r < 4; ++r) { m_i[r] = -1e30f; l_i[r] = 0.f; }

  for (int kt = 0; kt < S_; kt += 64) {
    // stage K tile: 64 keys x 128 d
#pragma unroll
    for (int it = 0; it < 4; ++it) {
      int c = it * 256 + tid;
      int key = c >> 4, d0 = (c & 15) * 8;
      *(h8*)&Ks[key * 136 + d0] =
          *(const h8*)&Kh[(b * S_ + kt + key) * D_ + h * HD_ + d0];
    }
    // stage V^T tile: 128 d x 64 keys (from pre-transposed Vt, fully coalesced)
#pragma unroll
    for (int it = 0; it < 4; ++it) {
      int c = it * 256 + tid;
      int d = c >> 3, k0 = (c & 7) * 8;
      *(h8*)&Vs[d * 72 + k0] = *(const h8*)&Vt[(bh * HD_ + d) * S_ + kt + k0];
    }
    __syncthreads();

    // S = Q K^T for this wave's 16 q-rows x 64 keys
    fx4 s[4];
#pragma unroll
    for (int j = 0; j < 4; ++j) {
      fx4 acc = {};
#pragma unroll
      for (int kk = 0; kk < 4; ++kk) {
        h8 bk = *(const h8*)&Ks[(j * 16 + l16) * 136 + kk * 32 + quad * 8];
        acc = __builtin_amdgcn_mfma_f32_16x16x32_f16(aq[kk], bk, acc, 0, 0, 0);
      }
      s[j] = acc;
    }
#pragma unroll
    for (int j = 0; j < 4; ++j)
#pragma unroll
      for (int r = 0; r < 4; ++r) s[j][r] *= SCALE;

    // online softmax (rows = quad*4 + r; reduce across the 16 lanes of the quad)
    float alpha[4];
#pragma unroll
    for (int r = 0; r < 4; ++r) {
      float mx = fmaxf(fmaxf(s[0][r], s[1][r]), fmaxf(s[2][r], s[3][r]));
#pragma unroll
      for (int off = 1; off < 16; off <<= 1) mx = fmaxf(mx, __shfl_xor(mx, off));
      float mnew = fmaxf(m_i[r], mx);
      alpha[r] = __expf(m_i[r] - mnew);
      m_i[r] = mnew;
      float rs = 0.f;
#pragma unroll
      for (int j = 0; j < 4; ++j) {
        float p = __expf(s[j][r] - mnew);
        s[j][r] = p;
        rs += p;
      }
#pragma unroll
      for (int off = 1; off < 16; off <<= 1) rs += __shfl_xor(rs, off);
      l_i[r] = l_i[r] * alpha[r] + rs;
    }

    // P -> LDS (C-layout -> A-layout round trip), rescale O
#pragma unroll
    for (int j = 0; j < 4; ++j)
#pragma unroll
      for (int r = 0; r < 4; ++r)
        Ps[(w * 16 + quad * 4 + r) * 72 + j * 16 + l16] = (_Float16)s[j][r];
#pragma unroll
    for (int jd = 0; jd < 8; ++jd)
#pragma unroll
      for (int r = 0; r < 4; ++r) o[jd][r] *= alpha[r];

    // O += P V
#pragma unroll
    for (int kk = 0; kk < 2; ++kk) {
      h8 ap = *(const h8*)&Ps[(w * 16 + l16) * 72 + kk * 32 + quad * 8];
#pragma unroll
      for (int jd = 0; jd < 8; ++jd) {
        h8 bv = *(const h8*)&Vs[(jd * 16 + l16) * 72 + kk * 32 + quad * 8];
        o[jd] = __builtin_amdgcn_mfma_f32_16x16x32_f16(ap, bv, o[jd], 0, 0, 0);
      }
    }
    __syncthreads();
  }

  // epilogue: O /= l
#pragma unroll
  for (int r = 0; r < 4; ++r) {
    float inv = 1.0f / l_i[r];
    int qrow = q0 + quad * 4 + r;
#pragma unroll
    for (int jd = 0; jd < 8; ++jd)
      Oh[(b * S_ + qrow) * D_ + h * HD_ + jd * 16 + l16] = (_Float16)(o[jd][r] * inv);
  }
}

extern "C" void kernel_launch(void* const* d_in, const int* in_sizes, int n_in,
                              void* d_out, int out_size, void* d_ws, size_t ws_size,
                              hipStream_t stream) {
  const float* hs = (const float*)d_in[0];
  const float* Wq = (const float*)d_in[1];
  const float* bq = (const float*)d_in[2];
  const float* Wk = (const float*)d_in[3];
  const float* bk = (const float*)d_in[4];
  const float* Wv = (const float*)d_in[5];
  const float* bv = (const float*)d_in[6];
  const float* Wo = (const float*)d_in[7];
  const float* bo = (const float*)d_in[8];
  float* out = (float*)d_out;

  const int MD = S_ * 4 * D_;  // 8388608 elements (B*S x D)
  const int WD = D_ * D_;      // 1048576
  _Float16* ws = (_Float16*)d_ws;
  _Float16* hs_h = ws;                    // MD
  _Float16* WtQ = hs_h + MD;              // 3*WD (Q,K,V transposed weights)
  _Float16* WtO = WtQ + 3 * WD;           // WD
  _Float16* QKVh = WtO + WD;              // 3*MD
  _Float16* Vt = QKVh + 3 * MD;           // MD
  _Float16* Oh = Vt + MD;                 // MD

  dim3 tb(32, 8);
  cast_f16_kernel<<<MD / 4 / 256, 256, 0, stream>>>(hs, hs_h, MD / 4);
  transpose_cast_w<<<dim3(32, 32), tb, 0, stream>>>(Wq, WtQ);
  transpose_cast_w<<<dim3(32, 32), tb, 0, stream>>>(Wk, WtQ + WD);
  transpose_cast_w<<<dim3(32, 32), tb, 0, stream>>>(Wv, WtQ + 2 * WD);
  transpose_cast_w<<<dim3(32, 32), tb, 0, stream>>>(Wo, WtO);

  gemm_qkv<<<dim3(8, 64, 3), 256, 0, stream>>>(hs_h, WtQ, bq, bk, bv, QKVh);
  transpose_v<<<dim3(S_ / 32, HD_ / 32, 32), tb, 0, stream>>>(QKVh + 2 * MD, Vt);
  attn_kernel<<<dim3(S_ / 64, 32), 256, 0, stream>>>(QKVh, QKVh + MD, Vt, Oh);
  gemm_out<<<dim3(8, 64), 256, 0, stream>>>(Oh, WtO, bo, out);
}